// Round 2
// baseline (1263.628 us; speedup 1.0000x reference)
//
#include <hip/hip_runtime.h>

// Problem constants
#define B_N   65536
#define D_N   784        // x / output feature dim
#define H_N   392        // hidden dim
#define L_N   32         // latent dim
#define OUT_IMG ((size_t)B_N * D_N)   // 51,380,224

#define HSTR  420        // hbuf row stride (ushorts). 420 ≡ 4 (mod 16) → quad bank
                         // step = 8 → conflict-free C-stores / ~2-way A-reads.

typedef unsigned short ushort_t;
typedef __attribute__((ext_vector_type(8))) short short8;   // 8 bf16 (4 VGPRs)
typedef __attribute__((ext_vector_type(4))) float f32x4;    // 4 fp32 acc

// ws region sizes (bf16 elements)
#define N_WE1  358400   // [25 kt][28 nt][64][8]   enc1: K=800, N=448
#define N_WEZ  26624    // [4 nt][13 kt][64][8]    emu+elv fused: N=64, K=416
#define N_WD1  13312    // [26 nt][64][8]          dec1: N=416, K=32
#define N_WDY  745472   // [13 kt][7 c][4 nw][4 tt][64][8]  dmu+dlv: Npairs=56, K=416
#define N_W16  (N_WE1 + N_WEZ + N_WD1 + N_WDY)   // 1,143,808 bf16
#define N_BIAS 2720     // 448 + 64 + 416 + 896 + 896 floats
#define WS_BYTES (N_W16*2 + N_BIAS*4)

__device__ __forceinline__ unsigned short f2bf(float f) {
  union { float f; unsigned u; } v; v.f = f;
  unsigned r = v.u + 0x7FFFu + ((v.u >> 16) & 1u);   // RNE
  return (unsigned short)(r >> 16);
}

// ---------------- prep: cast+pad+swizzle weights to MFMA B-fragment order ----------------
__global__ void vae_prep(const float* __restrict__ We1, const float* __restrict__ Wemu,
                         const float* __restrict__ Welv, const float* __restrict__ Wd1,
                         const float* __restrict__ Wdmu, const float* __restrict__ Wdlv,
                         const float* __restrict__ be1, const float* __restrict__ bemu,
                         const float* __restrict__ belv, const float* __restrict__ bd1,
                         const float* __restrict__ bdmu, const float* __restrict__ bdlv,
                         ushort_t* __restrict__ ws16, float* __restrict__ wsb,
                         float* __restrict__ scalar_out) {
  int idx = blockIdx.x * 256 + threadIdx.x;
  if (idx == 0) *scalar_out = 0.f;   // zero the scalar accumulator (d_out is poisoned)
  if (idx < N_W16) {
    float val;
    if (idx < N_WE1) {                         // enc1  W[n][k], n<392, k<784
      int e = idx; int j = e & 7, lane = (e >> 3) & 63, g = e >> 9;
      int nt = g % 28, kt = g / 28;
      int n = nt * 16 + (lane & 15), k = kt * 32 + ((lane >> 4) << 3) + j;
      val = (n < H_N && k < D_N) ? We1[n * D_N + k] : 0.f;
    } else if (idx < N_WE1 + N_WEZ) {          // emu(rows 0-31) + elv(rows 32-63), k<392
      int e = idx - N_WE1; int j = e & 7, lane = (e >> 3) & 63, g = e >> 9;
      int kt = g % 13, nt = g / 13;
      int n = nt * 16 + (lane & 15), k = kt * 32 + ((lane >> 4) << 3) + j;
      val = (k < H_N) ? (n < 32 ? Wemu[n * H_N + k] : Welv[(n - 32) * H_N + k]) : 0.f;
    } else if (idx < N_WE1 + N_WEZ + N_WD1) {  // dec1 W[n][k], n<392, k<32
      int e = idx - N_WE1 - N_WEZ; int j = e & 7, lane = (e >> 3) & 63, nt = e >> 9;
      int n = nt * 16 + (lane & 15), k = ((lane >> 4) << 3) + j;
      val = (n < H_N) ? Wd1[n * L_N + k] : 0.f;
    } else {                                   // dmu/dlv interleaved by pair
      int e = idx - N_WE1 - N_WEZ - N_WD1; int j = e & 7, lane = (e >> 3) & 63, g = e >> 9;
      int tt = g & 3, nw = (g >> 2) & 3, c = (g >> 4) % 7, kt = g / 112;
      int pair = nw * 14 + 2 * c + (tt >> 1);
      int d = pair * 16 + (lane & 15);
      int k = kt * 32 + ((lane >> 4) << 3) + j;
      val = (d < D_N && k < H_N) ? ((tt & 1) ? Wdlv[d * H_N + k] : Wdmu[d * H_N + k]) : 0.f;
    }
    ws16[idx] = f2bf(val);
  } else {
    int bi = idx - N_W16;
    if (bi < N_BIAS) {
      float val;
      if      (bi < 448)  val = (bi < H_N) ? be1[bi] : 0.f;
      else if (bi < 512)  { int i2 = bi - 448;  val = (i2 < 32) ? bemu[i2] : belv[i2 - 32]; }
      else if (bi < 928)  { int i2 = bi - 512;  val = (i2 < H_N) ? bd1[i2] : 0.f; }
      else if (bi < 1824) { int i2 = bi - 928;  val = (i2 < D_N) ? bdmu[i2] : 0.f; }
      else                { int i2 = bi - 1824; val = (i2 < D_N) ? bdlv[i2] : 0.f; }
      wsb[bi] = val;
    }
  }
}

// ---------------- fused VAE forward: 128 rows per block, 8 waves, 2 barriers ----------------
__global__ __launch_bounds__(512, 2) void vae_main(
    const float* __restrict__ x, const float* __restrict__ eps_z,
    const float* __restrict__ eps_y,
    const ushort_t* __restrict__ ws16, const float* __restrict__ wsb,
    float* __restrict__ out, float* __restrict__ scalar_out) {
  const ushort_t* We1t = ws16;
  const ushort_t* Wezt = ws16 + N_WE1;
  const ushort_t* Wd1t = Wezt + N_WEZ;
  const ushort_t* Wdyt = Wd1t + N_WD1;
  const float* be1p  = wsb;
  const float* bezp  = wsb + 448;
  const float* bd1p  = wsb + 512;
  const float* bdmup = wsb + 928;
  const float* bdlvp = wsb + 1824;

  __shared__ __align__(16) ushort_t hbuf[128 * HSTR];  // h then hd (bf16)
  __shared__ __align__(16) ushort_t zbuf[128 * 40];    // z (bf16), stride 40
  __shared__ float red[8];

  const int tid  = threadIdx.x;
  const int w    = tid >> 6;
  const int lane = tid & 63;
  const int quad = lane >> 4;
  const int l16  = lane & 15;
  const int mw   = w >> 2, nw = w & 3;   // 2x4 wave grid for stages 1,5
  const int rb   = blockIdx.x * 128;

  float kl_acc = 0.f, q_acc = 0.f, ld_acc = 0.f;

  // ================= stage 1: h = relu(x @ We1^T + b_e1)   M=128,N=448,K=800 =========
  // No LDS staging: A-frags built in-register from x (L1-served, 4x nw dup);
  // B-frags read directly from global (L2-resident, pre-swizzled frag order).
  f32x4 acc1[4][7];
  {
    f32x4 z4 = {0.f, 0.f, 0.f, 0.f};
#pragma unroll
    for (int i = 0; i < 4; ++i)
#pragma unroll
      for (int t = 0; t < 7; ++t) acc1[i][t] = z4;
  }
  const float* xp[4];
#pragma unroll
  for (int i = 0; i < 4; ++i)
    xp[i] = x + (size_t)(rb + mw * 64 + i * 16 + l16) * D_N + quad * 8;

#pragma unroll 2
  for (int kt = 0; kt < 24; ++kt) {
    short8 afr[4];
#pragma unroll
    for (int i = 0; i < 4; ++i) {
      const float4* px = (const float4*)(xp[i] + kt * 32);
      float4 v0 = px[0], v1 = px[1];
      union { int4 p; short8 s; } u;
      u.p.x = f2bf(v0.x) | ((unsigned)f2bf(v0.y) << 16);
      u.p.y = f2bf(v0.z) | ((unsigned)f2bf(v0.w) << 16);
      u.p.z = f2bf(v1.x) | ((unsigned)f2bf(v1.y) << 16);
      u.p.w = f2bf(v1.z) | ((unsigned)f2bf(v1.w) << 16);
      afr[i] = u.s;
    }
    __builtin_amdgcn_s_setprio(1);
#pragma unroll
    for (int t = 0; t < 7; ++t) {
      short8 bfr = *(const short8*)(We1t + ((kt * 28 + nw * 7 + t) * 64 + lane) * 8);
#pragma unroll
      for (int i = 0; i < 4; ++i)
        acc1[i][t] = __builtin_amdgcn_mfma_f32_16x16x32_bf16(afr[i], bfr, acc1[i][t], 0, 0, 0);
    }
    __builtin_amdgcn_s_setprio(0);
  }
  { // peeled kt=24: cols 768..799; only quads 0,1 are real (784..799 = K pad)
    short8 afr[4];
#pragma unroll
    for (int i = 0; i < 4; ++i) {
      union { int4 p; short8 s; } u;
      if (quad < 2) {
        const float4* px = (const float4*)(xp[i] + 24 * 32);
        float4 v0 = px[0], v1 = px[1];
        u.p.x = f2bf(v0.x) | ((unsigned)f2bf(v0.y) << 16);
        u.p.y = f2bf(v0.z) | ((unsigned)f2bf(v0.w) << 16);
        u.p.z = f2bf(v1.x) | ((unsigned)f2bf(v1.y) << 16);
        u.p.w = f2bf(v1.z) | ((unsigned)f2bf(v1.w) << 16);
      } else {
        u.p.x = 0; u.p.y = 0; u.p.z = 0; u.p.w = 0;
      }
      afr[i] = u.s;
    }
#pragma unroll
    for (int t = 0; t < 7; ++t) {
      short8 bfr = *(const short8*)(We1t + ((24 * 28 + nw * 7 + t) * 64 + lane) * 8);
#pragma unroll
      for (int i = 0; i < 4; ++i)
        acc1[i][t] = __builtin_amdgcn_mfma_f32_16x16x32_bf16(afr[i], bfr, acc1[i][t], 0, 0, 0);
    }
  }
  // bias + relu + store h to LDS (cols 0..415; 392..415 zero via zero-padded W/b)
#pragma unroll
  for (int t = 0; t < 7; ++t) {
    int ntg = nw * 7 + t;
    if (ntg < 26) {
      int n = ntg * 16 + l16;
      float bb = be1p[n];
#pragma unroll
      for (int i = 0; i < 4; ++i)
#pragma unroll
        for (int r = 0; r < 4; ++r) {
          int m = mw * 64 + i * 16 + quad * 4 + r;
          hbuf[m * HSTR + n] = f2bf(fmaxf(acc1[i][t][r] + bb, 0.f));
        }
    }
  }
  __syncthreads();   // barrier #1: h complete

  // ===== stage 2: [mu_z | logvar_z] = relu(h @ Wez^T + b)  per-wave 16 rows, N=64,K=416
  f32x4 acc2[4];
  {
    f32x4 z4 = {0.f, 0.f, 0.f, 0.f};
#pragma unroll
    for (int nt = 0; nt < 4; ++nt) acc2[nt] = z4;
  }
  for (int kt = 0; kt < 13; ++kt) {
    short8 a = *(const short8*)(hbuf + (16 * w + l16) * HSTR + kt * 32 + quad * 8);
#pragma unroll
    for (int nt = 0; nt < 4; ++nt) {
      short8 b = *(const short8*)(Wezt + ((nt * 13 + kt) * 64 + lane) * 8);
      acc2[nt] = __builtin_amdgcn_mfma_f32_16x16x32_bf16(a, b, acc2[nt], 0, 0, 0);
    }
  }
  // ===== stage 3: KL partials + z = mu + eps_z * exp(0.5*lv), z -> LDS (bf16)
  // zbuf rows 16w..16w+15 are wave-private (written and read by wave w only).
#pragma unroll
  for (int s = 0; s < 2; ++s) {
    float bmu = bezp[s * 16 + l16];
    float blv = bezp[32 + s * 16 + l16];
#pragma unroll
    for (int r = 0; r < 4; ++r) {
      float mu = fmaxf(acc2[s][r] + bmu, 0.f);
      float lv = fmaxf(acc2[s + 2][r] + blv, 0.f);
      int m = 16 * w + quad * 4 + r;
      int gm = rb + m;
      int l = s * 16 + l16;
      float e = __expf(lv);
      kl_acc += 0.5f * (mu * mu + e - __logf(1e-8f + e) - 1.f);
      float zz = mu + eps_z[gm * 32 + l] * __expf(0.5f * lv);
      zbuf[m * 40 + l] = f2bf(zz);
    }
  }
  // no barrier needed: zbuf + the hbuf rows stage 4 overwrites are wave-private

  // ===== stage 4: hd = relu(z @ Wd1^T + b_d1)  per-wave 16 rows, N=416, K=32 (1 tile)
  {
    short8 az = *(const short8*)(zbuf + (16 * w + l16) * 40 + quad * 8);
    for (int nt = 0; nt < 26; ++nt) {
      short8 b = *(const short8*)(Wd1t + (nt * 64 + lane) * 8);
      f32x4 a4 = {0.f, 0.f, 0.f, 0.f};
      a4 = __builtin_amdgcn_mfma_f32_16x16x32_bf16(az, b, a4, 0, 0, 0);
      int n = nt * 16 + l16;
      float bb = bd1p[n];
#pragma unroll
      for (int r = 0; r < 4; ++r) {
        int m = 16 * w + quad * 4 + r;
        hbuf[m * HSTR + n] = f2bf(fmaxf(a4[r] + bb, 0.f));   // overwrite own rows: safe
      }
    }
  }
  __syncthreads();   // barrier #2: hd complete

  // ===== stage 5/6: mu_y/logvar_y (paired tiles) + fused sigmoid/NLL epilogue
  // M=128, 56 d-pairs over 7 chunks (each wave: 2 pairs/chunk), K=416.
  // B-frags direct from global (L2-resident); hbuf is read-only -> no barriers at all.
  for (int c = 0; c < 7; ++c) {
    f32x4 acc5[4][4];
    {
      f32x4 z4 = {0.f, 0.f, 0.f, 0.f};
#pragma unroll
      for (int i = 0; i < 4; ++i)
#pragma unroll
        for (int tt = 0; tt < 4; ++tt) acc5[i][tt] = z4;
    }
#pragma unroll 2
    for (int kt = 0; kt < 13; ++kt) {
      short8 a[4], b[4];
#pragma unroll
      for (int i = 0; i < 4; ++i)
        a[i] = *(const short8*)(hbuf + (mw * 64 + i * 16 + l16) * HSTR + kt * 32 + quad * 8);
#pragma unroll
      for (int tt = 0; tt < 4; ++tt)
        b[tt] = *(const short8*)(Wdyt + ((kt * 112 + c * 16 + nw * 4 + tt) * 64 + lane) * 8);
      __builtin_amdgcn_s_setprio(1);
#pragma unroll
      for (int tt = 0; tt < 4; ++tt)
#pragma unroll
        for (int i = 0; i < 4; ++i)
          acc5[i][tt] = __builtin_amdgcn_mfma_f32_16x16x32_bf16(a[i], b[tt], acc5[i][tt], 0, 0, 0);
      __builtin_amdgcn_s_setprio(0);
    }
#pragma unroll
    for (int s = 0; s < 2; ++s) {
      int d = (nw * 14 + 2 * c + s) * 16 + l16;
      if (d < D_N) {   // uniform per wave (pair-granular padding)
        float bmu = bdmup[d], blv = bdlvp[d];
#pragma unroll
        for (int i = 0; i < 4; ++i) {
#pragma unroll
          for (int r = 0; r < 4; ++r) {
            int m = mw * 64 + i * 16 + quad * 4 + r;
            size_t gi = (size_t)(rb + m) * D_N + d;
            float mu = fmaxf(acc5[i][2 * s][r] + bmu, 0.f);
            float lv = fmaxf(acc5[i][2 * s + 1][r] + blv, 0.f);
            float sd = __expf(0.5f * lv);
            float tval = mu + eps_y[gi] * sd;
            out[gi] = __builtin_amdgcn_rcpf(1.f + __expf(-tval));
            float dq = x[gi] - mu;
            q_acc  += dq * dq * __builtin_amdgcn_rcpf(sd);  // (x-mu)^2 / exp(0.5*lv)
            ld_acc += 0.5f * lv;                            // logdet term
          }
        }
      }
    }
  }

  // ===== reduction: scalar = 0.5*D*ln(2pi) + (0.5/B)*(sum 0.5*lv + sum quad) + KL
  float v = (0.5f / (float)B_N) * (ld_acc + q_acc) + kl_acc;
#pragma unroll
  for (int off = 32; off; off >>= 1) v += __shfl_down(v, off, 64);
  if (lane == 0) red[w] = v;
  __syncthreads();
  if (tid == 0) {
    float tot = 0.f;
#pragma unroll
    for (int i = 0; i < 8; ++i) tot += red[i];
    if (blockIdx.x == 0) tot += 720.447808f;   // 0.5 * 784 * ln(2*pi)
    atomicAdd(scalar_out, tot);
  }
}

extern "C" void kernel_launch(void* const* d_in, const int* in_sizes, int n_in,
                              void* d_out, int out_size, void* d_ws, size_t ws_size,
                              hipStream_t stream) {
  const float* x     = (const float*)d_in[0];
  const float* eps_z = (const float*)d_in[1];
  const float* eps_y = (const float*)d_in[2];
  const float* We1   = (const float*)d_in[3];
  const float* be1   = (const float*)d_in[4];
  const float* Wemu  = (const float*)d_in[5];
  const float* bemu  = (const float*)d_in[6];
  const float* Welv  = (const float*)d_in[7];
  const float* belv  = (const float*)d_in[8];
  const float* Wd1   = (const float*)d_in[9];
  const float* bd1   = (const float*)d_in[10];
  const float* Wdmu  = (const float*)d_in[11];
  const float* bdmu  = (const float*)d_in[12];
  const float* Wdlv  = (const float*)d_in[13];
  const float* bdlv  = (const float*)d_in[14];

  float* out = (float*)d_out;
  float* scalar_out = out + OUT_IMG;

  ushort_t* ws16 = (ushort_t*)d_ws;
  float* wsb = (float*)((char*)d_ws + (size_t)N_W16 * 2);

  // prep: weight cast/pad/swizzle + bias pad + zero scalar slot
  int prep_total = N_W16 + N_BIAS;
  int prep_blocks = (prep_total + 255) / 256;
  vae_prep<<<prep_blocks, 256, 0, stream>>>(We1, Wemu, Welv, Wd1, Wdmu, Wdlv,
                                            be1, bemu, belv, bd1, bdmu, bdlv,
                                            ws16, wsb, scalar_out);

  // fused forward: 512 blocks x 512 threads, 128 rows/block
  vae_main<<<B_N / 128, 512, 0, stream>>>(x, eps_z, eps_y, ws16, wsb, out, scalar_out);
}

// Round 3
// 735.226 us; speedup vs baseline: 1.7187x; 1.7187x over previous
//
#include <hip/hip_runtime.h>

// Problem constants
#define B_N   65536
#define D_N   784        // x / output feature dim
#define H_N   392        // hidden dim
#define L_N   32         // latent dim
#define OUT_IMG ((size_t)B_N * D_N)   // 51,380,224

#define M_ROWS 64        // rows per block (was 128) -> LDS 79 KB -> 2 blocks/CU
#define HSTR   392       // hbuf row stride (ushorts). Cols >=392 read garbage that
                         // multiplies ZERO-padded weight rows (harmless); stores masked.

typedef unsigned short ushort_t;
typedef __attribute__((ext_vector_type(8))) short short8;   // 8 bf16 (4 VGPRs)
typedef __attribute__((ext_vector_type(4))) float f32x4;    // 4 fp32 acc

// ws region sizes (bf16 elements)
#define N_WE1  358400   // [25 kt][28 nt][64][8]   enc1: K=800, N=448
#define N_WEZ  26624    // [4 nt][13 kt][64][8]    emu+elv fused: N=64, K=416
#define N_WD1  13312    // [26 nt][64][8]          dec1: N=416, K=32
#define N_WDY  745472   // [13 kt][7 c][4 nw][4 tt][64][8]  dmu+dlv: Npairs=56, K=416
#define N_W16  (N_WE1 + N_WEZ + N_WD1 + N_WDY)   // 1,143,808 bf16
#define N_BIAS 2720     // 448 + 64 + 416 + 896 + 896 floats
#define WS_BYTES (N_W16*2 + N_BIAS*4)

__device__ __forceinline__ unsigned short f2bf(float f) {
  union { float f; unsigned u; } v; v.f = f;
  unsigned r = v.u + 0x7FFFu + ((v.u >> 16) & 1u);   // RNE
  return (unsigned short)(r >> 16);
}

__device__ __forceinline__ void gl2lds16(const void* g, void* l) {
  __builtin_amdgcn_global_load_lds(
      (const __attribute__((address_space(1))) unsigned int*)(unsigned long long)g,
      (__attribute__((address_space(3))) unsigned int*)(unsigned int)(unsigned long long)l,
      16, 0, 0);
}

// ---------------- prep: cast+pad+swizzle weights to MFMA B-fragment order ----------------
__global__ void vae_prep(const float* __restrict__ We1, const float* __restrict__ Wemu,
                         const float* __restrict__ Welv, const float* __restrict__ Wd1,
                         const float* __restrict__ Wdmu, const float* __restrict__ Wdlv,
                         const float* __restrict__ be1, const float* __restrict__ bemu,
                         const float* __restrict__ belv, const float* __restrict__ bd1,
                         const float* __restrict__ bdmu, const float* __restrict__ bdlv,
                         ushort_t* __restrict__ ws16, float* __restrict__ wsb,
                         float* __restrict__ scalar_out) {
  int idx = blockIdx.x * 256 + threadIdx.x;
  if (idx == 0) *scalar_out = 0.f;   // zero the scalar accumulator (d_out is poisoned)
  if (idx < N_W16) {
    float val;
    if (idx < N_WE1) {                         // enc1  W[n][k], n<392, k<784
      int e = idx; int j = e & 7, lane = (e >> 3) & 63, g = e >> 9;
      int nt = g % 28, kt = g / 28;
      int n = nt * 16 + (lane & 15), k = kt * 32 + ((lane >> 4) << 3) + j;
      val = (n < H_N && k < D_N) ? We1[n * D_N + k] : 0.f;
    } else if (idx < N_WE1 + N_WEZ) {          // emu(rows 0-31) + elv(rows 32-63), k<392
      int e = idx - N_WE1; int j = e & 7, lane = (e >> 3) & 63, g = e >> 9;
      int kt = g % 13, nt = g / 13;
      int n = nt * 16 + (lane & 15), k = kt * 32 + ((lane >> 4) << 3) + j;
      val = (k < H_N) ? (n < 32 ? Wemu[n * H_N + k] : Welv[(n - 32) * H_N + k]) : 0.f;
    } else if (idx < N_WE1 + N_WEZ + N_WD1) {  // dec1 W[n][k], n<392, k<32
      int e = idx - N_WE1 - N_WEZ; int j = e & 7, lane = (e >> 3) & 63, nt = e >> 9;
      int n = nt * 16 + (lane & 15), k = ((lane >> 4) << 3) + j;
      val = (n < H_N) ? Wd1[n * L_N + k] : 0.f;
    } else {                                   // dmu/dlv interleaved by pair
      int e = idx - N_WE1 - N_WEZ - N_WD1; int j = e & 7, lane = (e >> 3) & 63, g = e >> 9;
      int tt = g & 3, nw = (g >> 2) & 3, c = (g >> 4) % 7, kt = g / 112;
      int pair = nw * 14 + 2 * c + (tt >> 1);
      int d = pair * 16 + (lane & 15);
      int k = kt * 32 + ((lane >> 4) << 3) + j;
      val = (d < D_N && k < H_N) ? ((tt & 1) ? Wdlv[d * H_N + k] : Wdmu[d * H_N + k]) : 0.f;
    }
    ws16[idx] = f2bf(val);
  } else {
    int bi = idx - N_W16;
    if (bi < N_BIAS) {
      float val;
      if      (bi < 448)  val = (bi < H_N) ? be1[bi] : 0.f;
      else if (bi < 512)  { int i2 = bi - 448;  val = (i2 < 32) ? bemu[i2] : belv[i2 - 32]; }
      else if (bi < 928)  { int i2 = bi - 512;  val = (i2 < H_N) ? bd1[i2] : 0.f; }
      else if (bi < 1824) { int i2 = bi - 928;  val = (i2 < D_N) ? bdmu[i2] : 0.f; }
      else                { int i2 = bi - 1824; val = (i2 < D_N) ? bdlv[i2] : 0.f; }
      wsb[bi] = val;
    }
  }
}

// ---------------- fused VAE forward: 64 rows/block, 8 waves, 2 blocks/CU ----------------
__global__ __launch_bounds__(512, 4) void vae_main(
    const float* __restrict__ x, const float* __restrict__ eps_z,
    const float* __restrict__ eps_y,
    const ushort_t* __restrict__ ws16, const float* __restrict__ wsb,
    float* __restrict__ out, float* __restrict__ scalar_out) {
  const ushort_t* We1t = ws16;
  const ushort_t* Wezt = ws16 + N_WE1;
  const ushort_t* Wd1t = Wezt + N_WEZ;
  const ushort_t* Wdyt = Wd1t + N_WD1;
  const float* be1p  = wsb;
  const float* bezp  = wsb + 448;
  const float* bd1p  = wsb + 512;
  const float* bdmup = wsb + 928;
  const float* bdlvp = wsb + 1824;

  // LDS: 50,240 + 28,672 + 32 = 78,944 B  -> 2 blocks/CU
  __shared__ __align__(16) ushort_t hbuf[M_ROWS * HSTR + 32]; // h then hd (bf16) + pad
  __shared__ __align__(16) ushort_t wslab[28 * 512];          // W k-slab; zbuf aliases
  __shared__ float red[8];

  ushort_t* zb = wslab;   // z buffer (64 x 40 bf16 = 5,120 B), live only stages 3-4

  const int tid  = threadIdx.x;
  const int w    = tid >> 6;
  const int lane = tid & 63;
  const int quad = lane >> 4;
  const int l16  = lane & 15;
  const int mw   = w >> 2, nw = w & 3;   // 2x4 wave grid for stages 1,5
  const int rb   = blockIdx.x * M_ROWS;

  float kl_acc = 0.f, q_acc = 0.f, ld_acc = 0.f;

  // zero the hbuf tail pad (read by row 63's last A-frag tile; must be finite)
  if (tid < 32) hbuf[M_ROWS * HSTR + tid] = 0;

  // ================= stage 1: h = relu(x @ We1^T + b_e1)   M=64,N=448,K=800 =========
  // A-frags built in-register from x (L1-dedups the 4x nw duplication);
  // B staged via global_load_lds (wave-cooperative burst, amortized latency).
  f32x4 acc1[2][7];
  {
    f32x4 z4 = {0.f, 0.f, 0.f, 0.f};
#pragma unroll
    for (int i = 0; i < 2; ++i)
#pragma unroll
      for (int t = 0; t < 7; ++t) acc1[i][t] = z4;
  }
  const float* xp[2];
#pragma unroll
  for (int i = 0; i < 2; ++i)
    xp[i] = x + (size_t)(rb + mw * 32 + i * 16 + l16) * D_N + quad * 8;

  for (int kt = 0; kt < 25; ++kt) {
    __syncthreads();                       // protect previous iter's wslab reads
    // W slab: 28 KiB contiguous -> LDS (async, width 16)
#pragma unroll
    for (int i = 0; i < 4; ++i) {
      int g = i * 512 + tid;
      if (g < 1792) gl2lds16((const char*)We1t + kt * 28672 + g * 16, (char*)wslab + g * 16);
    }
    // x A-frags in-register
    short8 afr[2];
    {
      bool real = !(kt == 24 && quad >= 2);   // K pad 784..799
#pragma unroll
      for (int i = 0; i < 2; ++i) {
        union { int4 p; short8 s; } u;
        if (real) {
          const float4* px = (const float4*)(xp[i] + kt * 32);
          float4 v0 = px[0], v1 = px[1];
          u.p.x = f2bf(v0.x) | ((unsigned)f2bf(v0.y) << 16);
          u.p.y = f2bf(v0.z) | ((unsigned)f2bf(v0.w) << 16);
          u.p.z = f2bf(v1.x) | ((unsigned)f2bf(v1.y) << 16);
          u.p.w = f2bf(v1.z) | ((unsigned)f2bf(v1.w) << 16);
        } else {
          u.p.x = 0; u.p.y = 0; u.p.z = 0; u.p.w = 0;
        }
        afr[i] = u.s;
      }
    }
    __syncthreads();                       // slab ready
    __builtin_amdgcn_s_setprio(1);
#pragma unroll
    for (int t = 0; t < 7; ++t) {
      short8 bfr = *(const short8*)(wslab + ((nw * 7 + t) * 64 + lane) * 8);
#pragma unroll
      for (int i = 0; i < 2; ++i)
        acc1[i][t] = __builtin_amdgcn_mfma_f32_16x16x32_bf16(afr[i], bfr, acc1[i][t], 0, 0, 0);
    }
    __builtin_amdgcn_s_setprio(0);
  }
  // bias + relu + store h to LDS (only real cols n<392; stride 392)
#pragma unroll
  for (int t = 0; t < 7; ++t) {
    int ntg = nw * 7 + t;
    if (ntg < 25) {                        // tiles >=25 are entirely pad
      int n = ntg * 16 + l16;
      bool ok = (n < H_N);                 // tile 24 is half pad
      float bb = ok ? be1p[n] : 0.f;
#pragma unroll
      for (int i = 0; i < 2; ++i)
#pragma unroll
        for (int r = 0; r < 4; ++r) {
          int m = mw * 32 + i * 16 + quad * 4 + r;
          if (ok) hbuf[m * HSTR + n] = f2bf(fmaxf(acc1[i][t][r] + bb, 0.f));
        }
    }
  }
  __syncthreads();   // barrier: h complete (also covers pad zeroing)

  // ===== stage 2+3: [mu_z|logvar_z] + KL + z   (waves 0..3; 16 rows each; N=64,K=416)
  if (w < 4) {
    f32x4 acc2[4];
    {
      f32x4 z4 = {0.f, 0.f, 0.f, 0.f};
#pragma unroll
      for (int nt = 0; nt < 4; ++nt) acc2[nt] = z4;
    }
    for (int kt = 0; kt < 13; ++kt) {
      short8 a = *(const short8*)(hbuf + (16 * w + l16) * HSTR + kt * 32 + quad * 8);
#pragma unroll
      for (int nt = 0; nt < 4; ++nt) {
        short8 b = *(const short8*)(Wezt + ((nt * 13 + kt) * 64 + lane) * 8);
        acc2[nt] = __builtin_amdgcn_mfma_f32_16x16x32_bf16(a, b, acc2[nt], 0, 0, 0);
      }
    }
#pragma unroll
    for (int s = 0; s < 2; ++s) {
      float bmu = bezp[s * 16 + l16];
      float blv = bezp[32 + s * 16 + l16];
#pragma unroll
      for (int r = 0; r < 4; ++r) {
        float mu = fmaxf(acc2[s][r] + bmu, 0.f);
        float lv = fmaxf(acc2[s + 2][r] + blv, 0.f);
        int m = 16 * w + quad * 4 + r;
        int gm = rb + m;
        int l = s * 16 + l16;
        float e = __expf(lv);
        kl_acc += 0.5f * (mu * mu + e - __logf(1e-8f + e) - 1.f);
        float zz = mu + eps_z[gm * 32 + l] * __expf(0.5f * lv);
        zb[m * 40 + l] = f2bf(zz);
      }
    }
  }
  __syncthreads();   // barrier: z complete (stage 4 uses other waves' z; hbuf reads done)

  // ===== stage 4: hd = relu(z @ Wd1^T + b_d1)  all 8 waves: rows (w&3)*16, nt-half w>>2
  {
    const int rw = (w & 3) * 16;
    const int wh = w >> 2;
    short8 az = *(const short8*)(zb + (rw + l16) * 40 + quad * 8);
    for (int t2 = 0; t2 < 13; ++t2) {
      int nt = wh * 13 + t2;
      if (nt >= 25) continue;              // wave-uniform (wh=1, t2=12 only)
      short8 b = *(const short8*)(Wd1t + (nt * 64 + lane) * 8);
      f32x4 a4 = {0.f, 0.f, 0.f, 0.f};
      a4 = __builtin_amdgcn_mfma_f32_16x16x32_bf16(az, b, a4, 0, 0, 0);
      int n = nt * 16 + l16;
      bool ok = (n < H_N);
      float bb = ok ? bd1p[n] : 0.f;
#pragma unroll
      for (int r = 0; r < 4; ++r) {
        int m = rw + quad * 4 + r;
        if (ok) hbuf[m * HSTR + n] = f2bf(fmaxf(a4[r] + bb, 0.f));
      }
    }
  }
  __syncthreads();   // barrier: hd complete

  // ===== stage 5/6: mu_y/logvar_y (paired tiles) + fused sigmoid/NLL epilogue
  // M=64, 56 d-pairs over 7 chunks (each wave: 2 pairs/chunk), K=416, LDS-staged W.
  for (int c = 0; c < 7; ++c) {
    f32x4 acc5[2][4];
    {
      f32x4 z4 = {0.f, 0.f, 0.f, 0.f};
#pragma unroll
      for (int i = 0; i < 2; ++i)
#pragma unroll
        for (int tt = 0; tt < 4; ++tt) acc5[i][tt] = z4;
    }
    for (int kt = 0; kt < 13; ++kt) {
      __syncthreads();                     // protect previous slab reads
#pragma unroll
      for (int i = 0; i < 2; ++i) {
        int g = i * 512 + tid;
        gl2lds16((const char*)Wdyt + (kt * 7 + c) * 16384 + g * 16, (char*)wslab + g * 16);
      }
      __syncthreads();                     // slab ready
      short8 a[2];
#pragma unroll
      for (int i = 0; i < 2; ++i)
        a[i] = *(const short8*)(hbuf + (mw * 32 + i * 16 + l16) * HSTR + kt * 32 + quad * 8);
      __builtin_amdgcn_s_setprio(1);
#pragma unroll
      for (int tt = 0; tt < 4; ++tt) {
        short8 b = *(const short8*)(wslab + ((nw * 4 + tt) * 64 + lane) * 8);
#pragma unroll
        for (int i = 0; i < 2; ++i)
          acc5[i][tt] = __builtin_amdgcn_mfma_f32_16x16x32_bf16(a[i], b, acc5[i][tt], 0, 0, 0);
      }
      __builtin_amdgcn_s_setprio(0);
    }
#pragma unroll
    for (int s = 0; s < 2; ++s) {
      int d = (nw * 14 + 2 * c + s) * 16 + l16;
      if (d < D_N) {   // uniform per wave (pair-granular padding)
        float bmu = bdmup[d], blv = bdlvp[d];
#pragma unroll
        for (int i = 0; i < 2; ++i) {
#pragma unroll
          for (int r = 0; r < 4; ++r) {
            int m = mw * 32 + i * 16 + quad * 4 + r;
            size_t gi = (size_t)(rb + m) * D_N + d;
            float mu = fmaxf(acc5[i][2 * s][r] + bmu, 0.f);
            float lv = fmaxf(acc5[i][2 * s + 1][r] + blv, 0.f);
            float sd = __expf(0.5f * lv);
            float ey = __builtin_nontemporal_load(&eps_y[gi]);   // stream: don't cache
            float xx = __builtin_nontemporal_load(&x[gi]);
            float tval = mu + ey * sd;
            __builtin_nontemporal_store(__builtin_amdgcn_rcpf(1.f + __expf(-tval)), &out[gi]);
            float dq = xx - mu;
            q_acc  += dq * dq * __builtin_amdgcn_rcpf(sd);  // (x-mu)^2 / exp(0.5*lv)
            ld_acc += 0.5f * lv;                            // logdet term
          }
        }
      }
    }
  }

  // ===== reduction: scalar = 0.5*D*ln(2pi) + (0.5/B)*(sum 0.5*lv + sum quad) + KL
  float v = (0.5f / (float)B_N) * (ld_acc + q_acc) + kl_acc;
#pragma unroll
  for (int off = 32; off; off >>= 1) v += __shfl_down(v, off, 64);
  if (lane == 0) red[w] = v;
  __syncthreads();
  if (tid == 0) {
    float tot = 0.f;
#pragma unroll
    for (int i = 0; i < 8; ++i) tot += red[i];
    if (blockIdx.x == 0) tot += 720.447808f;   // 0.5 * 784 * ln(2*pi)
    atomicAdd(scalar_out, tot);
  }
}

extern "C" void kernel_launch(void* const* d_in, const int* in_sizes, int n_in,
                              void* d_out, int out_size, void* d_ws, size_t ws_size,
                              hipStream_t stream) {
  const float* x     = (const float*)d_in[0];
  const float* eps_z = (const float*)d_in[1];
  const float* eps_y = (const float*)d_in[2];
  const float* We1   = (const float*)d_in[3];
  const float* be1   = (const float*)d_in[4];
  const float* Wemu  = (const float*)d_in[5];
  const float* bemu  = (const float*)d_in[6];
  const float* Welv  = (const float*)d_in[7];
  const float* belv  = (const float*)d_in[8];
  const float* Wd1   = (const float*)d_in[9];
  const float* bd1   = (const float*)d_in[10];
  const float* Wdmu  = (const float*)d_in[11];
  const float* bdmu  = (const float*)d_in[12];
  const float* Wdlv  = (const float*)d_in[13];
  const float* bdlv  = (const float*)d_in[14];

  float* out = (float*)d_out;
  float* scalar_out = out + OUT_IMG;

  ushort_t* ws16 = (ushort_t*)d_ws;
  float* wsb = (float*)((char*)d_ws + (size_t)N_W16 * 2);

  // prep: weight cast/pad/swizzle + bias pad + zero scalar slot
  int prep_total = N_W16 + N_BIAS;
  int prep_blocks = (prep_total + 255) / 256;
  vae_prep<<<prep_blocks, 256, 0, stream>>>(We1, Wemu, Welv, Wd1, Wdmu, Wdlv,
                                            be1, bemu, belv, bd1, bdmu, bdlv,
                                            ws16, wsb, scalar_out);

  // fused forward: 1024 blocks x 512 threads, 64 rows/block
  vae_main<<<B_N / M_ROWS, 512, 0, stream>>>(x, eps_z, eps_y, ws16, wsb, out, scalar_out);
}